// Round 1
// 124.103 us; speedup vs baseline: 1.0839x; 1.0839x over previous
//
#include <hip/hip_runtime.h>

#define NROWS 131072
#define D 64
#define K 1024

typedef __attribute__((ext_vector_type(8))) short short8;
typedef __attribute__((ext_vector_type(4))) float f32x4;
typedef unsigned int u32;

// ws layout (bytes):
//   [0, 131072)        ehT  ushort[1024][64]  bf16 codebook, [code][d]
//   [131072, 135168)   e2g  float[1024]       = -0.5*||e_k||^2
//   [135168, 139264)   hist int[1024]
//   [139264, 155648)   wavesum float[4096]

__device__ __forceinline__ unsigned short f2bf_rne(float f) {
    u32 u = __float_as_uint(f);
    u += 0x7fff + ((u >> 16) & 1);   // round-to-nearest-even
    return (unsigned short)(u >> 16);
}

__global__ __launch_bounds__(256) void prep_kernel(const float* __restrict__ E,
                                                   unsigned short* __restrict__ ehT,
                                                   float* __restrict__ e2g,
                                                   int* __restrict__ hist) {
    const int k = blockIdx.x * 256 + threadIdx.x;   // 4 blocks, one thread per code
    float s = 0.f;
#pragma unroll
    for (int db = 0; db < 8; ++db) {
        short8 h8;
#pragma unroll
        for (int j = 0; j < 8; ++j) {
            float v = E[(db * 8 + j) * K + k];      // coalesced across lanes
            s = fmaf(v, v, s);
            h8[j] = (short)f2bf_rne(v);
        }
        *(short8*)(ehT + (size_t)k * D + db * 8) = h8;
    }
    e2g[k] = -0.5f * s;
    hist[k] = 0;
}

// R7 restructure: codebook-in-registers. 256 blocks x 1024 threads (16 waves),
// 512 rows/block in 4 chunks of 128. Wave w owns codes [w*64, w*64+64):
// 4 MFMA A-frag tiles (32 VGPR) + e2 float4 per tile used directly as the MFMA
// C operand (no acc-init movs). X is reg-staged (issue-early) into a
// double-buffered frag-order bf16 LDS buffer; 2 barriers per chunk; no
// global_load_lds DMA, no per-pass codebook restaging, 2x less LDS read.
// mfma(A=codes, B=rows) gives bitwise-identical scores to the previous
// mfma(A=rows, B=codes) kernel (same operands, same K-chain), so the packed
// score|code argmax and outputs are unchanged.
__global__ __launch_bounds__(1024) void score_kernel(const float* __restrict__ X,
                                                     const unsigned short* __restrict__ ehT,
                                                     const float* __restrict__ e2g,
                                                     int* __restrict__ hist,
                                                     float* __restrict__ wavesum,
                                                     float* __restrict__ q) {
    __shared__ unsigned short xbuf[2][8192];   // 2 x 16 KB: 128 rows x 64 d, frag order
    __shared__ float mrg[128 * 17];            // per-row packed best per wave (stride 17: conflict-free)
    __shared__ int idxl[512];                  // winning code per row

    const int tid = threadIdx.x;
    const int wave = tid >> 6;
    const int lane = tid & 63;
    const int quad = lane >> 4;
    const int lc = lane & 15;
    const size_t row0 = (size_t)blockIdx.x * 512;

    // ---- persistent codebook fragments: wave owns codes [wave*64, wave*64+64) ----
    const int cbase = wave * 64;
    short8 ae[4][2];      // [code-tile][kslice], lane: code=tile*16+lc, d=ks*32+quad*8..+8
    f32x4 e2f[4];         // lane: -0.5||e||^2 for codes tile*16+quad*4..+4 (MFMA C operand)
    u32 cb4[4];
#pragma unroll
    for (int ct = 0; ct < 4; ++ct) {
        const unsigned short* ap = ehT + ((size_t)(cbase + ct * 16 + lc) << 6) + quad * 8;
        ae[ct][0] = *(const short8*)(ap);
        ae[ct][1] = *(const short8*)(ap + 32);
        e2f[ct] = *(const f32x4*)(e2g + cbase + ct * 16 + quad * 4);
        cb4[ct] = (u32)(cbase + ct * 16 + quad * 4);
    }

    // ---- stage mapping: thread n -> slot n = (t=n>>7, o=(n>>4)&7, ls=n&15) ----
    // LDS byte n*16 holds bf16 X[t*16+ls][o*8..+8]; global read is fully
    // coalesced (4 lanes x 32 B cover each 128 B half-line).
    const int st = tid >> 7, so = (tid >> 4) & 7, sl = tid & 15;
    const float* sbase = X + (row0 + (size_t)(st * 16 + sl)) * D + so * 8;

    // ---- prologue: stage chunk 0 ----
    float4 La = *(const float4*)(sbase);
    float4 Lb = *(const float4*)(sbase + 4);
    {
        union { u32 u[4]; short8 v; } pk;
        pk.u[0] = __builtin_amdgcn_perm(__float_as_uint(La.y), __float_as_uint(La.x), 0x07060302);
        pk.u[1] = __builtin_amdgcn_perm(__float_as_uint(La.w), __float_as_uint(La.z), 0x07060302);
        pk.u[2] = __builtin_amdgcn_perm(__float_as_uint(Lb.y), __float_as_uint(Lb.x), 0x07060302);
        pk.u[3] = __builtin_amdgcn_perm(__float_as_uint(Lb.w), __float_as_uint(Lb.z), 0x07060302);
        *(short8*)((char*)&xbuf[0][0] + tid * 16) = pk.v;
    }
    __syncthreads();

    for (int c = 0; c < 4; ++c) {
        const int cur = c & 1;
        // issue-early global loads for chunk c+1 (land during compute; the
        // barrier's vmcnt drain is then free)
        if (c < 3) {
            La = *(const float4*)(sbase + (c + 1) * 8192);
            Lb = *(const float4*)(sbase + (c + 1) * 8192 + 4);
        }

        // ---- compute chunk c: 8 row-tiles x 4 code-tiles ----
        const char* bb = (const char*)&xbuf[cur][0];
#pragma unroll 2
        for (int t = 0; t < 8; ++t) {
            const char* bp = bb + t * 2048 + quad * 256 + lc * 16;
            short8 b0 = *(const short8*)(bp);           // ks0, conflict-free 1 KB/wave
            short8 b1 = *(const short8*)(bp + 1024);    // ks1
            float bt = -3.4e38f;
#pragma unroll
            for (int ct = 0; ct < 4; ++ct) {
                f32x4 acc = __builtin_amdgcn_mfma_f32_16x16x32_bf16(ae[ct][0], b0, e2f[ct], 0, 0, 0);
                acc = __builtin_amdgcn_mfma_f32_16x16x32_bf16(ae[ct][1], b1, acc, 0, 0, 0);
#pragma unroll
                for (int r = 0; r < 4; ++r) {
                    // acc[r] = score(code = cb4[ct]+r, xrow = t*16+lc)
                    float pkv = __uint_as_float((__float_as_uint(acc[r]) & 0xFFFFFC00u) | (cb4[ct] + r));
                    bt = fmaxf(bt, pkv);
                }
            }
            // reduce over the 4 quad-groups (codes) sharing xrow = lc
            bt = fmaxf(bt, __shfl_xor(bt, 16, 64));
            bt = fmaxf(bt, __shfl_xor(bt, 32, 64));
            if (lane < 16) mrg[(t * 16 + lane) * 17 + wave] = bt;
        }
        __syncthreads();   // merge visible; buf[cur^1] readers (chunk c-1) long done

        // ---- cross-wave merge + hist (2 waves) ∥ stage-write c+1 (all) ----
        if (tid < 128) {
            float m = mrg[tid * 17];
#pragma unroll
            for (int w = 1; w < 16; ++w) m = fmaxf(m, mrg[tid * 17 + w]);
            int kk = (int)(__float_as_uint(m) & 1023u);
            idxl[c * 128 + tid] = kk;
            atomicAdd(&hist[kk], 1);
        }
        if (c < 3) {
            union { u32 u[4]; short8 v; } pk;
            pk.u[0] = __builtin_amdgcn_perm(__float_as_uint(La.y), __float_as_uint(La.x), 0x07060302);
            pk.u[1] = __builtin_amdgcn_perm(__float_as_uint(La.w), __float_as_uint(La.z), 0x07060302);
            pk.u[2] = __builtin_amdgcn_perm(__float_as_uint(Lb.y), __float_as_uint(Lb.x), 0x07060302);
            pk.u[3] = __builtin_amdgcn_perm(__float_as_uint(Lb.w), __float_as_uint(Lb.z), 0x07060302);
            *(short8*)((char*)&xbuf[cur ^ 1][0] + tid * 16) = pk.v;
        }
        __syncthreads();   // staged chunk + idxl visible
    }

    // ---- coalesced epilogue: 8 sweeps x 64 rows (16 threads/row) ----
    float ls = 0.f;
    const int er = tid >> 4, el = tid & 15;
#pragma unroll 2
    for (int it = 0; it < 8; ++it) {
        int rl = it * 64 + er;
        int k = idxl[rl];                         // broadcast within 16-thread group
        size_t row = row0 + rl;
        float4 xv = *(const float4*)(X + row * D + el * 4);
        short4 ev = *(const short4*)((const char*)ehT + (size_t)k * 128 + el * 8);
        float e0 = __uint_as_float(((u32)(unsigned short)ev.x) << 16);
        float e1 = __uint_as_float(((u32)(unsigned short)ev.y) << 16);
        float e2 = __uint_as_float(((u32)(unsigned short)ev.z) << 16);
        float e3 = __uint_as_float(((u32)(unsigned short)ev.w) << 16);
        float4 o;
        float dx = e0 - xv.x; ls = fmaf(dx, dx, ls); o.x = xv.x + dx;
        float dy = e1 - xv.y; ls = fmaf(dy, dy, ls); o.y = xv.y + dy;
        float dz = e2 - xv.z; ls = fmaf(dz, dz, ls); o.z = xv.z + dz;
        float dw = e3 - xv.w; ls = fmaf(dw, dw, ls); o.w = xv.w + dw;
        *(float4*)(q + row * D + el * 4) = o;
    }
    for (int off = 32; off > 0; off >>= 1) ls += __shfl_down(ls, off, 64);
    if (lane == 0) wavesum[blockIdx.x * 16 + wave] = ls;
}

__global__ __launch_bounds__(1024) void finalize_kernel(const int* __restrict__ hist,
                                                        const float* __restrict__ wavesum,
                                                        float* __restrict__ out) {
    __shared__ float redH[16], redL[16];
    int tid = threadIdx.x;
    float p = (float)hist[tid] * (1.0f / (float)NROWS);
    float term = p * logf(p + 1e-10f);
    float ls = wavesum[tid] + wavesum[tid + 1024] + wavesum[tid + 2048] + wavesum[tid + 3072];
    for (int off = 32; off > 0; off >>= 1) {
        term += __shfl_down(term, off, 64);
        ls += __shfl_down(ls, off, 64);
    }
    int lane = tid & 63, wid = tid >> 6;
    if (lane == 0) { redH[wid] = term; redL[wid] = ls; }
    __syncthreads();
    if (tid == 0) {
        float H = 0.f, L = 0.f;
#pragma unroll
        for (int i = 0; i < 16; ++i) { H += redH[i]; L += redL[i]; }
        out[(size_t)NROWS * D + 0] = 2.0f * (L / (float)(NROWS * D));
        out[(size_t)NROWS * D + 1] = expf(-H);
    }
}

extern "C" void kernel_launch(void* const* d_in, const int* in_sizes, int n_in,
                              void* d_out, int out_size, void* d_ws, size_t ws_size,
                              hipStream_t stream) {
    const float* X = (const float*)d_in[0];   // [64,2048,64] fp32
    const float* E = (const float*)d_in[1];   // [64,1024]   fp32
    float* out = (float*)d_out;

    char* w = (char*)d_ws;
    unsigned short* ehT = (unsigned short*)(w + 0);
    float* e2g          = (float*)(w + 131072);
    int* hist           = (int*)(w + 135168);
    float* wavesum      = (float*)(w + 139264);

    prep_kernel<<<4, 256, 0, stream>>>(E, ehT, e2g, hist);
    score_kernel<<<256, 1024, 0, stream>>>(X, ehT, e2g, hist, wavesum, out);
    finalize_kernel<<<1, 1024, 0, stream>>>(hist, wavesum, out);
}